// Round 2
// baseline (284.709 us; speedup 1.0000x reference)
//
#include <hip/hip_runtime.h>
#include <hip/hip_bf16.h>
#include <hip/hip_fp16.h>

typedef _Float16 half8 __attribute__((ext_vector_type(8)));
typedef _Float16 half4 __attribute__((ext_vector_type(4)));
typedef float    floatx4 __attribute__((ext_vector_type(4)));

#define BM 128

// ---------------------------------------------------------------------------
// Kernel 1: W_l^T[n][k] = tri(||p_l[k] - p_{l+1}[n]||) / 16, fp16, layout [3][256][256]
// ---------------------------------------------------------------------------
__global__ void make_weights(const float* __restrict__ p0, const float* __restrict__ p1,
                             const float* __restrict__ p2, const float* __restrict__ p3,
                             _Float16* __restrict__ wt) {
    int idx = blockIdx.x * blockDim.x + threadIdx.x;   // (l*256 + n)*256 + k
    int k = idx & 255;
    int n = (idx >> 8) & 255;
    int l = idx >> 16;
    const float* P[4] = {p0, p1, p2, p3};
    const float* pa = P[l]     + k * 20;
    const float* pb = P[l + 1] + n * 20;
    float d2 = 0.0f;
    #pragma unroll
    for (int i = 0; i < 20; ++i) { float df = pa[i] - pb[i]; d2 += df * df; }
    float d = sqrtf(d2);
    float m = fmodf(d, 0.2f);                       // == np.mod for positive args
    float w = 10.0f * (0.05f - fabsf(m - 0.1f)) * 0.0625f;  // tri * 1/sqrt(256)
    wt[idx] = (_Float16)w;
}

// ---------------------------------------------------------------------------
// Kernel 2: fused 3-layer forward.
//   - One block = 128 rows x 256 cols. 8 waves (2x4 grid of 64x64 tiles).
//   - z lives in LDS only (64 KB, XOR-swizzled 16B chunks) -> 2 blocks/CU.
//   - W read straight from global (L2-resident, 384 KB total), register
//     double-buffered one K-step ahead. No per-K barriers: 5 barriers total.
//   - bias pre-loaded into the accumulator.
// ---------------------------------------------------------------------------
__global__ __launch_bounds__(512, 4) void pcn_fused(
    const float* __restrict__ x, const _Float16* __restrict__ wt,
    const float* __restrict__ b1, const float* __restrict__ b2,
    const float* __restrict__ b3, float* __restrict__ out) {

    // z[row][k]: byte = row*512 + (chunk ^ (row&7))*16 + within, chunk = k/8
    __shared__ __align__(16) _Float16 zlds[BM * 256];   // 65,536 B

    const int t    = threadIdx.x;
    const int lane = t & 63;
    const int wid  = t >> 6;      // 0..7
    const int wr   = wid >> 2;    // 0..1
    const int wc   = wid & 3;     // 0..3
    const int l15  = lane & 15;
    const int lg   = lane >> 4;   // 0..3
    const size_t row0 = (size_t)blockIdx.x * BM;

    char* zb = reinterpret_cast<char*>(zlds);

    // ---- stage x: 128x256 f32 -> fp16, swizzled. 2 passes x 8 float4/thread.
    #pragma unroll
    for (int pass = 0; pass < 2; ++pass) {
        floatx4 xr[8];
        #pragma unroll
        for (int i = 0; i < 8; ++i) {
            int g   = pass * 4096 + i * 512 + t;   // float4 index in [128][64]
            int row = g >> 6, c4 = g & 63;
            xr[i] = *reinterpret_cast<const floatx4*>(x + (row0 + row) * 256 + c4 * 4);
        }
        #pragma unroll
        for (int i = 0; i < 8; ++i) {
            int g   = pass * 4096 + i * 512 + t;
            int row = g >> 6, c4 = g & 63;
            half4 h;
            h[0] = (_Float16)xr[i][0]; h[1] = (_Float16)xr[i][1];
            h[2] = (_Float16)xr[i][2]; h[3] = (_Float16)xr[i][3];
            int chunk = (c4 >> 1) ^ (row & 7);
            *reinterpret_cast<half4*>(zb + row * 512 + chunk * 16 + (c4 & 1) * 8) = h;
        }
    }
    __syncthreads();

    floatx4 acc[4][4];

    for (int l = 0; l < 3; ++l) {
        const float* bias = (l == 0) ? b1 : (l == 1) ? b2 : b3;

        // bias -> accumulator init (broadcast along rows)
        #pragma unroll
        for (int nf = 0; nf < 4; ++nf) {
            const float bv = bias[wc * 64 + nf * 16 + l15];
            #pragma unroll
            for (int mf = 0; mf < 4; ++mf)
                acc[mf][nf] = floatx4{bv, bv, bv, bv};
        }

        const _Float16* wl = wt + ((size_t)l << 16);
        // per-nf W row base (elements); k-offset added per step
        half8 bb[2][4];
        #pragma unroll
        for (int nf = 0; nf < 4; ++nf)
            bb[0][nf] = *reinterpret_cast<const half8*>(
                wl + (wc * 64 + nf * 16 + l15) * 256 + lg * 8);

        #pragma unroll
        for (int s = 0; s < 8; ++s) {            // K-step of 32
            // prefetch next K-step's B fragments (register double-buffer)
            if (s < 7) {
                #pragma unroll
                for (int nf = 0; nf < 4; ++nf)
                    bb[(s + 1) & 1][nf] = *reinterpret_cast<const half8*>(
                        wl + (wc * 64 + nf * 16 + l15) * 256 + (s + 1) * 32 + lg * 8);
            }
            // A fragments from swizzled LDS
            const int vchunk = (s * 4 + lg) ^ (l15 & 7);
            half8 a[4];
            #pragma unroll
            for (int mf = 0; mf < 4; ++mf)
                a[mf] = *reinterpret_cast<const half8*>(
                    zb + (wr * 64 + mf * 16 + l15) * 512 + vchunk * 16);
            #pragma unroll
            for (int mf = 0; mf < 4; ++mf)
                #pragma unroll
                for (int nf = 0; nf < 4; ++nf)
                    acc[mf][nf] = __builtin_amdgcn_mfma_f32_16x16x32_f16(
                        a[mf], bb[s & 1][nf], acc[mf][nf], 0, 0, 0);
        }

        __syncthreads();   // all reads of zlds complete

        if (l < 2) {
            // relu + cvt -> zlds (bias already in acc)
            #pragma unroll
            for (int nf = 0; nf < 4; ++nf) {
                const int n = wc * 64 + nf * 16 + l15;
                #pragma unroll
                for (int mf = 0; mf < 4; ++mf) {
                    const int mrow = wr * 64 + mf * 16 + lg * 4;
                    #pragma unroll
                    for (int r = 0; r < 4; ++r) {
                        float v = fmaxf(acc[mf][nf][r], 0.0f);
                        const int row = mrow + r;
                        const int byte = row * 512 + (((n >> 3) ^ (row & 7)) << 4)
                                       + (n & 7) * 2;
                        *reinterpret_cast<_Float16*>(zb + byte) = (_Float16)v;
                    }
                }
            }
            __syncthreads();
        } else {
            // final layer: f32 out (bias already in acc)
            #pragma unroll
            for (int nf = 0; nf < 4; ++nf) {
                const int n = wc * 64 + nf * 16 + l15;
                #pragma unroll
                for (int mf = 0; mf < 4; ++mf) {
                    const size_t mrow = row0 + wr * 64 + mf * 16 + lg * 4;
                    #pragma unroll
                    for (int r = 0; r < 4; ++r)
                        out[(mrow + r) * 256 + n] = acc[mf][nf][r];
                }
            }
        }
    }
}

extern "C" void kernel_launch(void* const* d_in, const int* in_sizes, int n_in,
                              void* d_out, int out_size, void* d_ws, size_t ws_size,
                              hipStream_t stream) {
    const float* x  = (const float*)d_in[0];
    const float* p0 = (const float*)d_in[1];
    const float* p1 = (const float*)d_in[2];
    const float* p2 = (const float*)d_in[3];
    const float* p3 = (const float*)d_in[4];
    const float* b1 = (const float*)d_in[5];
    const float* b2 = (const float*)d_in[6];
    const float* b3 = (const float*)d_in[7];
    float* out = (float*)d_out;
    _Float16* wt = (_Float16*)d_ws;              // 3*256*256*2 = 384 KB scratch

    const int B = in_sizes[0] / 256;             // 131072

    make_weights<<<3 * 256 * 256 / 256, 256, 0, stream>>>(p0, p1, p2, p3, wt);
    pcn_fused<<<B / BM, 512, 0, stream>>>(x, wt, b1, b2, b3, out);
}

// Round 3
// 219.887 us; speedup vs baseline: 1.2948x; 1.2948x over previous
//
#include <hip/hip_runtime.h>
#include <hip/hip_bf16.h>
#include <hip/hip_fp16.h>

typedef _Float16 half8 __attribute__((ext_vector_type(8)));
typedef _Float16 half4 __attribute__((ext_vector_type(4)));
typedef float    floatx4 __attribute__((ext_vector_type(4)));

#define BM 64

// ---------------------------------------------------------------------------
// Kernel 1: W_l^T[n][k] = tri(||p_l[k] - p_{l+1}[n]||) / 16, fp16, layout [3][256][256]
// ---------------------------------------------------------------------------
__global__ void make_weights(const float* __restrict__ p0, const float* __restrict__ p1,
                             const float* __restrict__ p2, const float* __restrict__ p3,
                             _Float16* __restrict__ wt) {
    int idx = blockIdx.x * blockDim.x + threadIdx.x;   // (l*256 + n)*256 + k
    int k = idx & 255;
    int n = (idx >> 8) & 255;
    int l = idx >> 16;
    const float* P[4] = {p0, p1, p2, p3};
    const float* pa = P[l]     + k * 20;
    const float* pb = P[l + 1] + n * 20;
    float d2 = 0.0f;
    #pragma unroll
    for (int i = 0; i < 20; ++i) { float df = pa[i] - pb[i]; d2 += df * df; }
    float d = sqrtf(d2);
    float m = fmodf(d, 0.2f);                       // == np.mod for positive args
    float w = 10.0f * (0.05f - fabsf(m - 0.1f)) * 0.0625f;  // tri * 1/sqrt(256)
    wt[idx] = (_Float16)w;
}

// ---------------------------------------------------------------------------
// Kernel 2: fused 3-layer forward.
//   - One block = 64 rows x 256 cols, 512 threads, 8 waves in 2x4 grid of
//     32x64 tiles -> acc is only 32 regs/wave; total demand ~105 < 128.
//   - z in 32 KB XOR-swizzled LDS; W direct from global (L2-resident, 384 KB).
//   - 2 blocks/CU co-resident (reg- and LDS-wise) to keep HBM streaming
//     during the other block's compute/barrier phases. 6 barriers total.
// ---------------------------------------------------------------------------
__global__ __launch_bounds__(512, 4) void pcn_fused(
    const float* __restrict__ x, const _Float16* __restrict__ wt,
    const float* __restrict__ b1, const float* __restrict__ b2,
    const float* __restrict__ b3, float* __restrict__ out) {

    // z[row][k]: byte = row*512 + ((k/8) ^ (row&7))*16 + (k&7)*2
    __shared__ __align__(16) _Float16 zlds[BM * 256];   // 32,768 B

    const int t    = threadIdx.x;
    const int lane = t & 63;
    const int wid  = t >> 6;      // 0..7
    const int wr   = wid >> 2;    // 0..1   (32-row tile)
    const int wc   = wid & 3;     // 0..3   (64-col tile)
    const int l15  = lane & 15;
    const int lg   = lane >> 4;   // 0..3
    const size_t row0 = (size_t)blockIdx.x * BM;

    char* zb = reinterpret_cast<char*>(zlds);

    // ---- stage x: 64x256 f32 -> fp16 swizzled. 8 float4/thread, load-all-then-write.
    {
        floatx4 xr[8];
        #pragma unroll
        for (int i = 0; i < 8; ++i) {
            int g   = i * 512 + t;        // float4 index in [64][64]
            int row = g >> 6, c4 = g & 63;
            xr[i] = *reinterpret_cast<const floatx4*>(x + (row0 + row) * 256 + c4 * 4);
        }
        #pragma unroll
        for (int i = 0; i < 8; ++i) {
            int g   = i * 512 + t;
            int row = g >> 6, c4 = g & 63;
            half4 h;
            h[0] = (_Float16)xr[i][0]; h[1] = (_Float16)xr[i][1];
            h[2] = (_Float16)xr[i][2]; h[3] = (_Float16)xr[i][3];
            int chunk = (c4 >> 1) ^ (row & 7);
            *reinterpret_cast<half4*>(zb + row * 512 + chunk * 16 + (c4 & 1) * 8) = h;
        }
    }
    __syncthreads();

    floatx4 acc[2][4];

    for (int l = 0; l < 3; ++l) {
        const float* bias = (l == 0) ? b1 : (l == 1) ? b2 : b3;

        // bias -> accumulator init (broadcast along rows)
        #pragma unroll
        for (int nf = 0; nf < 4; ++nf) {
            const float bv = bias[wc * 64 + nf * 16 + l15];
            #pragma unroll
            for (int mf = 0; mf < 2; ++mf)
                acc[mf][nf] = floatx4{bv, bv, bv, bv};
        }

        // W fragment base: row n = wc*64 + nf*16 + l15, k = s*32 + lg*8
        const _Float16* wbase = wt + ((size_t)l << 16) + (wc * 64 + l15) * 256 + lg * 8;

        half8 bb[2][4];
        #pragma unroll
        for (int nf = 0; nf < 4; ++nf)
            bb[0][nf] = *reinterpret_cast<const half8*>(wbase + nf * 4096);

        #pragma unroll
        for (int s = 0; s < 8; ++s) {            // K-step of 32
            if (s < 7) {
                #pragma unroll
                for (int nf = 0; nf < 4; ++nf)
                    bb[(s + 1) & 1][nf] = *reinterpret_cast<const half8*>(
                        wbase + nf * 4096 + (s + 1) * 32);
            }
            const int vchunk = (s * 4 + lg) ^ (l15 & 7);
            half8 a[2];
            #pragma unroll
            for (int mf = 0; mf < 2; ++mf)
                a[mf] = *reinterpret_cast<const half8*>(
                    zb + (wr * 32 + mf * 16 + l15) * 512 + vchunk * 16);
            #pragma unroll
            for (int mf = 0; mf < 2; ++mf)
                #pragma unroll
                for (int nf = 0; nf < 4; ++nf)
                    acc[mf][nf] = __builtin_amdgcn_mfma_f32_16x16x32_f16(
                        a[mf], bb[s & 1][nf], acc[mf][nf], 0, 0, 0);
        }

        __syncthreads();   // all reads of zlds complete

        if (l < 2) {
            // relu + cvt -> zlds (bias already in acc)
            #pragma unroll
            for (int nf = 0; nf < 4; ++nf) {
                const int n = wc * 64 + nf * 16 + l15;
                #pragma unroll
                for (int mf = 0; mf < 2; ++mf) {
                    const int mrow = wr * 32 + mf * 16 + lg * 4;
                    #pragma unroll
                    for (int r = 0; r < 4; ++r) {
                        float v = fmaxf(acc[mf][nf][r], 0.0f);
                        const int row  = mrow + r;
                        const int byte = row * 512 + (((n >> 3) ^ (row & 7)) << 4)
                                       + (n & 7) * 2;
                        *reinterpret_cast<_Float16*>(zb + byte) = (_Float16)v;
                    }
                }
            }
            __syncthreads();
        } else {
            // final layer: f32 out (bias already in acc)
            #pragma unroll
            for (int nf = 0; nf < 4; ++nf) {
                const int n = wc * 64 + nf * 16 + l15;
                #pragma unroll
                for (int mf = 0; mf < 2; ++mf) {
                    const size_t mrow = row0 + wr * 32 + mf * 16 + lg * 4;
                    #pragma unroll
                    for (int r = 0; r < 4; ++r)
                        out[(mrow + r) * 256 + n] = acc[mf][nf][r];
                }
            }
        }
    }
}

extern "C" void kernel_launch(void* const* d_in, const int* in_sizes, int n_in,
                              void* d_out, int out_size, void* d_ws, size_t ws_size,
                              hipStream_t stream) {
    const float* x  = (const float*)d_in[0];
    const float* p0 = (const float*)d_in[1];
    const float* p1 = (const float*)d_in[2];
    const float* p2 = (const float*)d_in[3];
    const float* p3 = (const float*)d_in[4];
    const float* b1 = (const float*)d_in[5];
    const float* b2 = (const float*)d_in[6];
    const float* b3 = (const float*)d_in[7];
    float* out = (float*)d_out;
    _Float16* wt = (_Float16*)d_ws;              // 3*256*256*2 = 384 KB scratch

    const int B = in_sizes[0] / 256;             // 131072

    make_weights<<<3 * 256 * 256 / 256, 256, 0, stream>>>(p0, p1, p2, p3, wt);
    pcn_fused<<<B / BM, 512, 0, stream>>>(x, wt, b1, b2, b3, out);
}

// Round 4
// 97.645 us; speedup vs baseline: 2.9158x; 2.2519x over previous
//
#include <hip/hip_runtime.h>
#include <hip/hip_bf16.h>
#include <hip/hip_fp16.h>

typedef _Float16 half8 __attribute__((ext_vector_type(8)));
typedef _Float16 half4 __attribute__((ext_vector_type(4)));
typedef float    floatx4 __attribute__((ext_vector_type(4)));

#define BM 64

// ---------------------------------------------------------------------------
// Kernel 1: W in MFMA-fragment order. Element index:
//   idx = ((((l*4 + wc)*8 + s)*4 + nf)*64 + lane), value block = 8 halves (16 B)
//   content: W^T[n][k] * scale with n = wc*64+nf*16+(lane&15),
//            k = s*32 + (lane>>4)*8 + j,  j = 0..7
// so a wave's B-fragment load is contiguous: base + lane*16.
// ---------------------------------------------------------------------------
__global__ void make_weights_frag(const float* __restrict__ p0, const float* __restrict__ p1,
                                  const float* __restrict__ p2, const float* __restrict__ p3,
                                  _Float16* __restrict__ wt) {
    int idx  = blockIdx.x * blockDim.x + threadIdx.x;   // 0 .. 24575
    int lane = idx & 63;
    int nf   = (idx >> 6) & 3;
    int s    = (idx >> 8) & 7;
    int wc   = (idx >> 11) & 3;
    int l    = idx >> 13;
    int n  = wc * 64 + nf * 16 + (lane & 15);
    int k0 = s * 32 + (lane >> 4) * 8;
    const float* P[4] = {p0, p1, p2, p3};
    const float* pb = P[l + 1] + n * 20;
    float pbr[20];
    #pragma unroll
    for (int i = 0; i < 20; ++i) pbr[i] = pb[i];
    half8 o;
    #pragma unroll
    for (int j = 0; j < 8; ++j) {
        const float* pa = P[l] + (k0 + j) * 20;
        float d2 = 0.f;
        #pragma unroll
        for (int i = 0; i < 20; ++i) { float df = pa[i] - pbr[i]; d2 += df * df; }
        float d = sqrtf(d2);
        float m = fmodf(d, 0.2f);                            // == np.mod, d >= 0
        o[j] = (_Float16)(10.0f * (0.05f - fabsf(m - 0.1f)) * 0.0625f);
    }
    *reinterpret_cast<half8*>(wt + (size_t)idx * 8) = o;
}

// ---------------------------------------------------------------------------
// Kernel 2: fused 3-layer forward.
//   - Block = 64 rows x 256 cols, 512 threads, 8 waves (2x4 grid of 32x64).
//   - z in 32 KB XOR-swizzled LDS; W from global in fragment order
//     (wave-contiguous 1 KB loads), register double-buffered per K-step.
//   - Next layer's first W fragments prefetched before the boundary barrier.
//   - 2 blocks/CU co-resident; 6 barriers total; bias folded into acc init.
// ---------------------------------------------------------------------------
__global__ __launch_bounds__(512, 4) void pcn_fused(
    const float* __restrict__ x, const _Float16* __restrict__ wt,
    const float* __restrict__ b1, const float* __restrict__ b2,
    const float* __restrict__ b3, float* __restrict__ out) {

    // z[row][k]: byte = row*512 + ((k/8) ^ (row&7))*16 + (k&7)*2
    __shared__ __align__(16) _Float16 zlds[BM * 256];   // 32,768 B

    const int t    = threadIdx.x;
    const int lane = t & 63;
    const int wid  = t >> 6;      // 0..7
    const int wr   = wid >> 2;    // 0..1   (32-row tile)
    const int wc   = wid & 3;     // 0..3   (64-col tile)
    const int l15  = lane & 15;
    const int lg   = lane >> 4;   // 0..3
    const size_t row0 = (size_t)blockIdx.x * BM;

    char* zb = reinterpret_cast<char*>(zlds);

    // W slice for this wave's wc, layer 0: 16384 elements per (l,wc)
    const _Float16* wl = wt + ((size_t)wc << 14);

    half8 bb[2][4];
    // earliest possible: layer 0, step 0 fragments (contiguous 1 KB per load)
    #pragma unroll
    for (int nf = 0; nf < 4; ++nf)
        bb[0][nf] = *reinterpret_cast<const half8*>(wl + nf * 512 + lane * 8);

    // ---- stage x: 64x256 f32 -> fp16 swizzled. 8 float4/thread.
    {
        floatx4 xr[8];
        #pragma unroll
        for (int i = 0; i < 8; ++i) {
            int g   = i * 512 + t;        // float4 index in [64][64]
            int row = g >> 6, c4 = g & 63;
            xr[i] = *reinterpret_cast<const floatx4*>(x + (row0 + row) * 256 + c4 * 4);
        }
        #pragma unroll
        for (int i = 0; i < 8; ++i) {
            int g   = i * 512 + t;
            int row = g >> 6, c4 = g & 63;
            half4 h;
            h[0] = (_Float16)xr[i][0]; h[1] = (_Float16)xr[i][1];
            h[2] = (_Float16)xr[i][2]; h[3] = (_Float16)xr[i][3];
            int chunk = (c4 >> 1) ^ (row & 7);
            *reinterpret_cast<half4*>(zb + row * 512 + chunk * 16 + (c4 & 1) * 8) = h;
        }
    }
    __syncthreads();

    floatx4 acc[2][4];

    for (int l = 0; l < 3; ++l) {
        const float* bias = (l == 0) ? b1 : (l == 1) ? b2 : b3;

        // bias -> accumulator init (broadcast along rows)
        #pragma unroll
        for (int nf = 0; nf < 4; ++nf) {
            const float bv = bias[wc * 64 + nf * 16 + l15];
            #pragma unroll
            for (int mf = 0; mf < 2; ++mf)
                acc[mf][nf] = floatx4{bv, bv, bv, bv};
        }

        #pragma unroll
        for (int s = 0; s < 8; ++s) {            // K-step of 32
            // prefetch next K-step's fragments (contiguous, register dbuf)
            if (s < 7) {
                #pragma unroll
                for (int nf = 0; nf < 4; ++nf)
                    bb[(s + 1) & 1][nf] = *reinterpret_cast<const half8*>(
                        wl + (s + 1) * 2048 + nf * 512 + lane * 8);
            }
            const int vchunk = (s * 4 + lg) ^ (l15 & 7);
            half8 a[2];
            #pragma unroll
            for (int mf = 0; mf < 2; ++mf)
                a[mf] = *reinterpret_cast<const half8*>(
                    zb + (wr * 32 + mf * 16 + l15) * 512 + vchunk * 16);
            #pragma unroll
            for (int mf = 0; mf < 2; ++mf)
                #pragma unroll
                for (int nf = 0; nf < 4; ++nf)
                    acc[mf][nf] = __builtin_amdgcn_mfma_f32_16x16x32_f16(
                        a[mf], bb[s & 1][nf], acc[mf][nf], 0, 0, 0);
        }

        // issue next layer's step-0 fragments BEFORE the barrier: latency
        // hides under the epilogue + barriers. bb[0] is dead after step 6.
        if (l < 2) {
            wl += (size_t)4 << 14;   // next layer, same wc
            #pragma unroll
            for (int nf = 0; nf < 4; ++nf)
                bb[0][nf] = *reinterpret_cast<const half8*>(wl + nf * 512 + lane * 8);
        }

        __syncthreads();   // all reads of zlds complete

        if (l < 2) {
            // relu + cvt -> zlds (bias already in acc)
            #pragma unroll
            for (int nf = 0; nf < 4; ++nf) {
                const int n = wc * 64 + nf * 16 + l15;
                #pragma unroll
                for (int mf = 0; mf < 2; ++mf) {
                    const int mrow = wr * 32 + mf * 16 + lg * 4;
                    #pragma unroll
                    for (int r = 0; r < 4; ++r) {
                        float v = fmaxf(acc[mf][nf][r], 0.0f);
                        const int row  = mrow + r;
                        const int byte = row * 512 + (((n >> 3) ^ (row & 7)) << 4)
                                       + (n & 7) * 2;
                        *reinterpret_cast<_Float16*>(zb + byte) = (_Float16)v;
                    }
                }
            }
            __syncthreads();
        } else {
            // final layer: f32 out (bias already in acc)
            #pragma unroll
            for (int nf = 0; nf < 4; ++nf) {
                const int n = wc * 64 + nf * 16 + l15;
                #pragma unroll
                for (int mf = 0; mf < 2; ++mf) {
                    const size_t mrow = row0 + wr * 32 + mf * 16 + lg * 4;
                    #pragma unroll
                    for (int r = 0; r < 4; ++r)
                        out[(mrow + r) * 256 + n] = acc[mf][nf][r];
                }
            }
        }
    }
}

extern "C" void kernel_launch(void* const* d_in, const int* in_sizes, int n_in,
                              void* d_out, int out_size, void* d_ws, size_t ws_size,
                              hipStream_t stream) {
    const float* x  = (const float*)d_in[0];
    const float* p0 = (const float*)d_in[1];
    const float* p1 = (const float*)d_in[2];
    const float* p2 = (const float*)d_in[3];
    const float* p3 = (const float*)d_in[4];
    const float* b1 = (const float*)d_in[5];
    const float* b2 = (const float*)d_in[6];
    const float* b3 = (const float*)d_in[7];
    float* out = (float*)d_out;
    _Float16* wt = (_Float16*)d_ws;              // 3*4*8*4*64*8 = 196608 halves = 384 KB

    const int B = in_sizes[0] / 256;             // 131072

    make_weights_frag<<<96, 256, 0, stream>>>(p0, p1, p2, p3, wt);
    pcn_fused<<<B / BM, 512, 0, stream>>>(x, wt, b1, b2, b3, out);
}